// Round 9
// baseline (951.934 us; speedup 1.0000x reference)
//
#include <hip/hip_runtime.h>

// Problem constants
constexpr int Bn  = 128;
constexpr int Tn  = 48000;
constexpr int NFn = 2999;   // fast frames
constexpr int NSn = 999;    // slow frames
constexpr int G3n = 192;    // 3*GH
constexpr int GHn = 64;

typedef float f2 __attribute__((ext_vector_type(2)));
typedef float f4 __attribute__((ext_vector_type(4)));

// lgkmcnt-only block barrier (r2-proven). Does NOT drain vmcnt, so the
// gru's hs stores and prefetched globals stay in flight across phases.
#define LBAR()                                                 \
  do {                                                         \
    asm volatile("s_waitcnt lgkmcnt(0)" ::: "memory");         \
    __builtin_amdgcn_s_barrier();                              \
    asm volatile("" ::: "memory");                             \
  } while (0)

__device__ __forceinline__ float fsigmoid(float v) {
  return __fdividef(1.0f, 1.0f + __expf(-v));
}
__device__ __forceinline__ float ftanh_f(float v) {
  return 1.0f - __fdividef(2.0f, __expf(2.0f * v) + 1.0f);
}

// ---------------------------------------------------------------------------
// Producer: waves 1-2 of a gru block compute chunk c (32 t-steps) of GI for
// batch b into an LDS ring slot. Wave w handles t_local [tg2*16, tg2*16+16).
// Each wave stages ONLY its own xs slice (816 floats incl. 48-float overlap,
// duplicate identical writes are benign) => wave-local RAW only, no cross-
// producer sync. k ascending 0..95 per output => bitwise-identical to the
// original gi_kernel accumulation.
// ---------------------------------------------------------------------------
__device__ __forceinline__ void produce_chunk(const float* __restrict__ x,
                                              int b, int c,
                                              float* __restrict__ ring_slot,
                                              float* __restrict__ xs,
                                              const float* __restrict__ WT,
                                              int tg2, int lane, f4 bias4) {
  const int nt   = min(32, NSn - c * 32);
  const int span = (nt - 1) * 48 + 96;
  for (int i = lane; i < 816; i += 64) {
    const int ii = tg2 * 768 + i;
    xs[ii] = (ii < span) ? x[(size_t)b * Tn + (size_t)c * 1536 + ii] : 0.0f;
  }
  __builtin_amdgcn_wave_barrier();
  asm volatile("s_waitcnt lgkmcnt(0)" ::: "memory");

  if (lane < 48) {
    const int j0 = lane * 4;          // gate-row quad, covers j 0..191
    f4 acc[16];
#pragma unroll
    for (int u = 0; u < 16; ++u) acc[u] = bias4;
    for (int kc = 0; kc < 96; kc += 4) {
      f4 wq[4];
#pragma unroll
      for (int kk = 0; kk < 4; ++kk)
        wq[kk] = *(const f4*)&WT[(kc + kk) * 196 + j0];
      f4 xq[16];
#pragma unroll
      for (int u = 0; u < 16; ++u)
        xq[u] = *(const f4*)&xs[(tg2 * 16 + u) * 48 + kc];   // uniform -> bcast
#pragma unroll
      for (int u = 0; u < 16; ++u) {
#pragma unroll
        for (int kk = 0; kk < 4; ++kk) {
          const float xv = xq[u][kk];
          acc[u][0] = fmaf(xv, wq[kk][0], acc[u][0]);
          acc[u][1] = fmaf(xv, wq[kk][1], acc[u][1]);
          acc[u][2] = fmaf(xv, wq[kk][2], acc[u][2]);
          acc[u][3] = fmaf(xv, wq[kk][3], acc[u][3]);
        }
      }
    }
#pragma unroll
    for (int u = 0; u < 16; ++u) {
      const int tl = tg2 * 16 + u;
      if (tl < nt) *(f4*)&ring_slot[tl * 192 + j0] = acc[u];
    }
  }
}

// ---------------------------------------------------------------------------
// FUSED kernel, 192 threads/block:
//  blocks [0,128): wave 0 = gru (b = blockIdx.x); waves 1-2 = GI producers
//    feeding a 2-slot LDS ring. GI never goes to HBM. One LBAR per 32-step
//    phase. LDS: WT 75264B + ring 49152B + xs 6336B + hbuf 256B = 131008B
//    -> 1 block/CU -> gru keeps its proven 1-wave/SIMD regime.
//  blocks [128, 1152): U filler — wave w computes U chunk (ub&7)*3+w for
//    b = ub>>3 (identical math to r4's fat filler).
// No inter-block dependencies -> no cooperative launch, no dispatch-order
// or XCD-coherence assumptions.
// ---------------------------------------------------------------------------
constexpr int UCHUNK = 125;

__global__ __attribute__((amdgpu_flat_work_group_size(192, 192),
                          amdgpu_waves_per_eu(1, 1),
                          amdgpu_num_vgpr(256)))
void fused_kernel(const float* __restrict__ x,
                  const float* __restrict__ W_ih,
                  const float* __restrict__ b_ih,
                  const float* __restrict__ W_hh,
                  const float* __restrict__ b_hh,
                  const float* __restrict__ W1,
                  const float* __restrict__ b1,
                  float* __restrict__ hs,
                  float* __restrict__ U) {
  __shared__ __align__(16) float smem[32752];   // 131008 B
  const int tid  = threadIdx.x;
  const int wid  = tid >> 6;
  const int lane = tid & 63;

  if (blockIdx.x >= Bn) {
    // ---------------- U path (3 independent waves) ----------------
    const int ub = blockIdx.x - Bn;      // 0..1023
    const int b  = ub >> 3;
    const int ch = (ub & 7) * 3 + wid;   // 0..23
    const int fA = ch * UCHUNK;
    const int fE = min(fA + UCHUNK, NFn);
    float* xu = smem + wid * 2016;
    const int nsamp = (fE - fA - 1) * 16 + 32;
    for (int i = lane; i < nsamp; i += 64)
      xu[i] = x[(size_t)b * Tn + fA * 16 + i];
    f4 w1f[8];
#pragma unroll
    for (int i = 0; i < 8; ++i)
      w1f[i] = *(const f4*)&W1[(size_t)lane * 64 + 4 * i];
    const float bo = b1[lane];
    __builtin_amdgcn_wave_barrier();
    asm volatile("s_waitcnt lgkmcnt(0)" ::: "memory");

    float* Up = U + ((size_t)b * NFn) * GHn + lane;
    for (int f = fA; f < fE; ++f) {
      const f4* xq2 = (const f4*)&xu[(f - fA) * 16];
      float a0 = bo, a1 = 0.f, a2 = 0.f, a3 = 0.f;
#pragma unroll
      for (int i = 0; i < 8; ++i) {
        f4 xv = xq2[i];
        a0 = fmaf(xv[0], w1f[i][0], a0);
        a1 = fmaf(xv[1], w1f[i][1], a1);
        a2 = fmaf(xv[2], w1f[i][2], a2);
        a3 = fmaf(xv[3], w1f[i][3], a3);
      }
      Up[(size_t)f * GHn] = (a0 + a1) + (a2 + a3);
    }
    return;
  }

  // ---------------- gru + producers ----------------
  const int b = blockIdx.x;
  float* WT   = smem;            // [96][196]
  float* ring = smem + 18816;    // [2][32][192]
  float* xs   = smem + 31104;    // [1584]
  float* hbuf = smem + 32688;    // [64]

  // one-time W_ih -> WT[k][j] (all 192 threads; f4 coalesced global reads)
  for (int e4 = tid * 4; e4 < 192 * 96; e4 += 192 * 4) {
    f4 v = *(const f4*)&W_ih[e4];
    const int j = e4 / 96, k = e4 - j * 96;
#pragma unroll
    for (int cc = 0; cc < 4; ++cc) WT[(k + cc) * 196 + j] = v[cc];
  }
  LBAR();  // B1: WT visible

  f2 wr2[32], wz2[32], wn2[32];
  float br = 0.f, bz = 0.f, bn = 0.f;
  f4 bias4 = {0.f, 0.f, 0.f, 0.f};
  const int tg2 = wid - 1;

  if (wid == 0) {
    const int j = lane;
    const f2* Wr = (const f2*)(W_hh + (size_t)j * 64);
    const f2* Wz = (const f2*)(W_hh + (size_t)(j + 64) * 64);
    const f2* Wn = (const f2*)(W_hh + (size_t)(j + 128) * 64);
#pragma unroll
    for (int q = 0; q < 32; ++q) { wr2[q] = Wr[q]; wz2[q] = Wz[q]; wn2[q] = Wn[q]; }
#pragma unroll
    for (int q = 0; q < 32; ++q) {
      asm volatile("" : "+v"(wr2[q]));
      asm volatile("" : "+v"(wz2[q]));
      asm volatile("" : "+v"(wn2[q]));
    }
    br = b_hh[j]; bz = b_hh[j + 64]; bn = b_hh[j + 128];
    hbuf[j] = 0.0f;
  } else {
    if (lane < 48) bias4 = *(const f4*)&b_ih[lane * 4];
    produce_chunk(x, b, 0, ring, xs, WT, tg2, lane, bias4);
  }
  LBAR();  // B2: chunk 0 ready, hbuf zeroed

  float hj = 0.0f;
  float* hsp = hs + (size_t)b * NSn * GHn;

  for (int p = 0; p < 32; ++p) {
    if (wid == 0) {
      __builtin_amdgcn_s_setprio(1);         // favor the serial pole (r8 win)
      const int j  = lane;
      const int nt = min(32, NSn - p * 32);
      const float* rs = ring + (p & 1) * 6144;
      for (int tt = 0; tt < nt; ++tt) {
        const float* grow = rs + tt * 192;
        const float pr0 = grow[j];           // 3 conflict-free b32 LDS reads
        const float pz0 = grow[64 + j];
        const float pn0 = grow[128 + j];

        const f2* h2 = (const f2*)hbuf;
        f2 ar0 = {0.f, 0.f}, ar1 = {0.f, 0.f}, ar2 = {0.f, 0.f}, ar3 = {0.f, 0.f};
        f2 az0 = {0.f, 0.f}, az1 = {0.f, 0.f}, az2 = {0.f, 0.f}, az3 = {0.f, 0.f};
        f2 an0 = {0.f, 0.f}, an1 = {0.f, 0.f}, an2 = {0.f, 0.f}, an3 = {0.f, 0.f};
#pragma unroll
        for (int q = 0; q < 8; ++q) {
          f2 h0 = h2[q * 4 + 0], h1 = h2[q * 4 + 1], h2v = h2[q * 4 + 2], h3 = h2[q * 4 + 3];
          ar0 += wr2[q * 4 + 0] * h0; ar1 += wr2[q * 4 + 1] * h1;
          ar2 += wr2[q * 4 + 2] * h2v; ar3 += wr2[q * 4 + 3] * h3;
          az0 += wz2[q * 4 + 0] * h0; az1 += wz2[q * 4 + 1] * h1;
          az2 += wz2[q * 4 + 2] * h2v; az3 += wz2[q * 4 + 3] * h3;
          an0 += wn2[q * 4 + 0] * h0; an1 += wn2[q * 4 + 1] * h1;
          an2 += wn2[q * 4 + 2] * h2v; an3 += wn2[q * 4 + 3] * h3;
        }
        f2 sr = (ar0 + ar1) + (ar2 + ar3);
        f2 sz = (az0 + az1) + (az2 + az3);
        f2 sn = (an0 + an1) + (an2 + an3);

        float r = fsigmoid(pr0 + br + sr.x + sr.y);
        float z = fsigmoid(pz0 + bz + sz.x + sz.y);
        float n = ftanh_f(fmaf(r, bn + sn.x + sn.y, pn0));
        float hn = fmaf(z, hj - n, n);       // (1-z)*n + z*h

        __builtin_amdgcn_wave_barrier();
        hbuf[j] = hn;
        __builtin_amdgcn_wave_barrier();
        hj = hn;
        hsp[(size_t)(p * 32 + tt) * GHn + j] = hn;
      }
      __builtin_amdgcn_s_setprio(0);
    } else if (p + 1 < 32) {
      produce_chunk(x, b, p + 1, ring + ((p + 1) & 1) * 6144, xs, WT,
                    tg2, lane, bias4);
    }
    LBAR();  // chunk p+1 ready; slot p&1 free for reuse next phase
  }
}

// ---------------------------------------------------------------------------
// d_kernel: d[b,ts,o] = (c_s @ W1_cond^T), c_s = hs @ W_cs^T + b_cs  (proven)
// ---------------------------------------------------------------------------
__global__ __launch_bounds__(256) void d_kernel(const float* __restrict__ hs,
                                                const float* __restrict__ W_cs,
                                                const float* __restrict__ b_cs,
                                                const float* __restrict__ W1,
                                                float* __restrict__ d) {
  __shared__ __align__(16) float WcT[64 * 36];   // [k][i] stride 36
  __shared__ __align__(16) float W1cT[32 * 68];  // [i][o] stride 68
  __shared__ __align__(16) float hsl[32 * 65];   // [t][k] stride 65
  __shared__ __align__(16) float cloc[32 * 36];  // [t][i] stride 36
  __shared__ __align__(16) float bcs[32];
  const int tile = blockIdx.x;   // 0..31
  const int b    = blockIdx.y;
  const int t0   = tile * 32;
  const int nt   = min(32, NSn - t0);
  const int tid  = threadIdx.x;

  for (int e = tid; e < 32 * 64; e += 256) {
    int i = e >> 6, k = e & 63;
    WcT[k * 36 + i] = W_cs[e];
  }
  for (int e = tid; e < 64 * 32; e += 256) {
    int o = e >> 5, i = e & 31;
    W1cT[i * 68 + o] = W1[(size_t)o * 64 + 32 + i];
  }
  for (int e = tid; e < nt * 64; e += 256) {
    int t = e >> 6, k = e & 63;
    hsl[t * 65 + k] = hs[((size_t)b * NSn + t0 + t) * GHn + k];
  }
  if (tid < 32) bcs[tid] = b_cs[tid];
  __syncthreads();

  {
    const int iq = tid & 7;
    const int t  = tid >> 3;
    if (t < nt) {
      float4 acc = *(const float4*)&bcs[iq * 4];
      const float* hr = &hsl[t * 65];
#pragma unroll 4
      for (int k = 0; k < 64; ++k) {
        float hv = hr[k];
        float4 w = *(const float4*)&WcT[k * 36 + iq * 4];
        acc.x = fmaf(w.x, hv, acc.x);
        acc.y = fmaf(w.y, hv, acc.y);
        acc.z = fmaf(w.z, hv, acc.z);
        acc.w = fmaf(w.w, hv, acc.w);
      }
      *(float4*)&cloc[t * 36 + iq * 4] = acc;
    }
  }
  __syncthreads();

  for (int it = tid; it < 32 * 16; it += 256) {
    const int oq = it & 15;
    const int t  = it >> 4;
    if (t < nt) {
      float a0 = 0.f, a1 = 0.f, a2 = 0.f, a3 = 0.f;
      const float* cr = &cloc[t * 36];
#pragma unroll 4
      for (int i = 0; i < 32; ++i) {
        float cv = cr[i];
        float4 w = *(const float4*)&W1cT[i * 68 + oq * 4];
        a0 = fmaf(w.x, cv, a0);
        a1 = fmaf(w.y, cv, a1);
        a2 = fmaf(w.z, cv, a2);
        a3 = fmaf(w.w, cv, a3);
      }
      float4 st = make_float4(a0, a1, a2, a3);
      *(float4*)&d[((size_t)b * NSn + t0 + t) * GHn + oq * 4] = st;
    }
  }
}

// ---------------------------------------------------------------------------
// out2: h = relu(U + d[ts]), y = h@W2^T + b2, overlap-add  (proven)
// ---------------------------------------------------------------------------
__global__ __launch_bounds__(256) void out2_kernel(const float* __restrict__ U,
                                                   const float* __restrict__ d,
                                                   const float* __restrict__ W2,
                                                   const float* __restrict__ b2,
                                                   float* __restrict__ out) {
  __shared__ __align__(16) float h1loc[33 * 68];
  __shared__ __align__(16) float W2T[64 * 36];
  __shared__ __align__(16) float yloc[33 * 32];
  __shared__ __align__(16) float dloc[12][68];
  __shared__ __align__(16) float bb2[32];

  const int fb  = blockIdx.x;
  const int b   = blockIdx.y;
  const int f0  = fb * 32;
  const int nf  = min(33, NFn - f0);
  const int tid = threadIdx.x;
  const int ts0 = max(f0 / 3 - 1, 0);

  for (int e = tid; e < 32 * 64; e += 256) {
    int o = e >> 6, k = e & 63;
    W2T[k * 36 + o] = W2[e];
  }
  if (tid < 32) bb2[tid] = b2[tid];
  for (int e = tid; e < 12 * 64; e += 256) {
    int ti = e >> 6, o = e & 63;
    int ts = min(ts0 + ti, NSn - 1);
    dloc[ti][o] = d[((size_t)b * NSn + ts) * GHn + o];
  }
  __syncthreads();

  for (int it = tid; it < 33 * 16; it += 256) {
    const int lf = it >> 4, oq = it & 15;
    const int f  = f0 + lf;
    f4 s = {0.f, 0.f, 0.f, 0.f};
    if (f < NFn) {
      f4 u  = *(const f4*)&U[((size_t)b * NFn + f) * GHn + oq * 4];
      const int ti = max(f / 3 - 1, 0) - ts0;
      f4 dv = *(const f4*)&dloc[ti][oq * 4];
      s = u + dv;
#pragma unroll
      for (int c = 0; c < 4; ++c) s[c] = fmaxf(s[c], 0.f);
    }
    *(f4*)&h1loc[lf * 68 + oq * 4] = s;
  }
  __syncthreads();

  for (int it = tid; it < 33 * 8; it += 256) {
    const int lf = it >> 3, oq = it & 7;
    float4 acc = *(const float4*)&bb2[oq * 4];
    const float* hr = &h1loc[lf * 68];
#pragma unroll 4
    for (int k = 0; k < 64; ++k) {
      float hv = hr[k];
      float4 w = *(const float4*)&W2T[k * 36 + oq * 4];
      acc.x = fmaf(w.x, hv, acc.x);
      acc.y = fmaf(w.y, hv, acc.y);
      acc.z = fmaf(w.z, hv, acc.z);
      acc.w = fmaf(w.w, hv, acc.w);
    }
    *(float4*)&yloc[lf * 32 + oq * 4] = acc;
  }
  __syncthreads();

  const int s0 = f0 * 16 + 16;
  const int s1 = min(s0 + 512, Tn);
  for (int s = s0 + tid; s < s1; s += 256) {
    int f1  = s >> 4;
    int o1  = s & 15;
    int lf1 = f1 - f0;
    float v = yloc[(lf1 - 1) * 32 + o1 + 16];
    if (lf1 < nf) v += yloc[lf1 * 32 + o1];
    out[(size_t)b * Tn + s] = v;
  }
  if (fb == 0 && tid < 16) out[(size_t)b * Tn + tid] = yloc[tid];
}

// ---------------------------------------------------------------------------
// Fallback kernels (small-ws only): round-0 proven pipeline
// ---------------------------------------------------------------------------
__global__ __launch_bounds__(192) void gi_kernel(const float* __restrict__ x,
                                                 const float* __restrict__ W_ih,
                                                 const float* __restrict__ b_ih,
                                                 float* __restrict__ GI) {
  __shared__ __align__(16) float WT[48 * 196];
  __shared__ __align__(16) float xs[1584];
  const int tile = blockIdx.x;
  const int b    = blockIdx.y;
  const int t0   = tile * 32;
  const int nt   = min(32, NSn - t0);
  const int tid  = threadIdx.x;

  const int span = (nt - 1) * 48 + 96;
  for (int i = tid; i < 1584; i += 192)
    xs[i] = (i < span) ? x[(size_t)b * Tn + t0 * 48 + i] : 0.0f;

  const int jq = tid % 48;
  const int tg = tid / 48;
  const int j0 = jq * 4;

  float acc[8][4];
#pragma unroll
  for (int u = 0; u < 8; ++u)
#pragma unroll
    for (int jj = 0; jj < 4; ++jj) acc[u][jj] = b_ih[j0 + jj];

  for (int half = 0; half < 2; ++half) {
    __syncthreads();
    for (int e = tid; e < 192 * 48; e += 192) {
      int j = e / 48, k = e % 48;
      WT[k * 196 + j] = W_ih[j * 96 + half * 48 + k];
    }
    __syncthreads();
    for (int k = 0; k < 48; ++k) {
      float4 w = *(const float4*)&WT[k * 196 + j0];
#pragma unroll
      for (int u = 0; u < 8; ++u) {
        float xv = xs[(tg * 8 + u) * 48 + half * 48 + k];
        acc[u][0] = fmaf(xv, w.x, acc[u][0]);
        acc[u][1] = fmaf(xv, w.y, acc[u][1]);
        acc[u][2] = fmaf(xv, w.z, acc[u][2]);
        acc[u][3] = fmaf(xv, w.w, acc[u][3]);
      }
    }
  }

#pragma unroll
  for (int u = 0; u < 8; ++u) {
    int tl = tg * 8 + u;
    if (tl < nt) {
      float4 st = make_float4(acc[u][0], acc[u][1], acc[u][2], acc[u][3]);
      *(float4*)&GI[(size_t)(b * NSn + t0 + tl) * G3n + j0] = st;
    }
  }
}

__global__ __attribute__((amdgpu_flat_work_group_size(64, 64),
                          amdgpu_waves_per_eu(1, 1),
                          amdgpu_num_vgpr(256)))
void gru_kernel(const float* __restrict__ GI,
                const float* __restrict__ W_hh,
                const float* __restrict__ b_hh,
                float* __restrict__ hs) {
  __shared__ __align__(16) float hbuf[64];
  const int b = blockIdx.x;
  const int j = threadIdx.x;

  f2 wr2[32], wz2[32], wn2[32];
  const f2* Wr = (const f2*)(W_hh + (size_t)j * 64);
  const f2* Wz = (const f2*)(W_hh + (size_t)(j + 64) * 64);
  const f2* Wn = (const f2*)(W_hh + (size_t)(j + 128) * 64);
#pragma unroll
  for (int q = 0; q < 32; ++q) { wr2[q] = Wr[q]; wz2[q] = Wz[q]; wn2[q] = Wn[q]; }
#pragma unroll
  for (int q = 0; q < 32; ++q) {
    asm volatile("" : "+v"(wr2[q]));
    asm volatile("" : "+v"(wz2[q]));
    asm volatile("" : "+v"(wn2[q]));
  }
  const float br = b_hh[j], bz = b_hh[j + 64], bn = b_hh[j + 128];

  hbuf[j] = 0.0f;
  float hj = 0.0f;
  __builtin_amdgcn_wave_barrier();

  const float* gp = GI + (size_t)b * NSn * G3n;
  float* hsp = hs + (size_t)b * NSn * GHn;

  float pr0, pr1, pr2, pz0, pz1, pz2, pn0, pn1, pn2;
  pr0 = gp[0 * G3n + j];       pz0 = gp[0 * G3n + 64 + j];  pn0 = gp[0 * G3n + 128 + j];
  pr1 = gp[1 * G3n + j];       pz1 = gp[1 * G3n + 64 + j];  pn1 = gp[1 * G3n + 128 + j];

  for (int t = 0; t < NSn; ++t) {
    const size_t off = (size_t)min(t + 2, NSn - 1) * G3n;
    pr2 = gp[off + j];
    pz2 = gp[off + 64 + j];
    pn2 = gp[off + 128 + j];

    const f2* h2 = (const f2*)hbuf;
    f2 ar0 = {0.f, 0.f}, ar1 = {0.f, 0.f}, ar2 = {0.f, 0.f}, ar3 = {0.f, 0.f};
    f2 az0 = {0.f, 0.f}, az1 = {0.f, 0.f}, az2 = {0.f, 0.f}, az3 = {0.f, 0.f};
    f2 an0 = {0.f, 0.f}, an1 = {0.f, 0.f}, an2 = {0.f, 0.f}, an3 = {0.f, 0.f};
#pragma unroll
    for (int q = 0; q < 8; ++q) {
      f2 h0 = h2[q * 4 + 0], h1 = h2[q * 4 + 1], h2v = h2[q * 4 + 2], h3 = h2[q * 4 + 3];
      ar0 += wr2[q * 4 + 0] * h0; ar1 += wr2[q * 4 + 1] * h1;
      ar2 += wr2[q * 4 + 2] * h2v; ar3 += wr2[q * 4 + 3] * h3;
      az0 += wz2[q * 4 + 0] * h0; az1 += wz2[q * 4 + 1] * h1;
      az2 += wz2[q * 4 + 2] * h2v; az3 += wz2[q * 4 + 3] * h3;
      an0 += wn2[q * 4 + 0] * h0; an1 += wn2[q * 4 + 1] * h1;
      an2 += wn2[q * 4 + 2] * h2v; an3 += wn2[q * 4 + 3] * h3;
    }
    f2 sr = (ar0 + ar1) + (ar2 + ar3);
    f2 sz = (az0 + az1) + (az2 + az3);
    f2 sn = (an0 + an1) + (an2 + an3);

    float r = fsigmoid(pr0 + br + sr.x + sr.y);
    float z = fsigmoid(pz0 + bz + sz.x + sz.y);
    float n = ftanh_f(fmaf(r, bn + sn.x + sn.y, pn0));
    float hn = fmaf(z, hj - n, n);

    __builtin_amdgcn_wave_barrier();
    hbuf[j] = hn;
    __builtin_amdgcn_wave_barrier();
    hj = hn;
    hsp[(size_t)t * GHn + j] = hn;

    pr0 = pr1; pr1 = pr2;
    pz0 = pz1; pz1 = pz2;
    pn0 = pn1; pn1 = pn2;
  }
}

__global__ __launch_bounds__(256) void cs_kernel(const float* __restrict__ hs,
                                                 const float* __restrict__ W_cs,
                                                 const float* __restrict__ b_cs,
                                                 float* __restrict__ cs) {
  __shared__ __align__(16) float WcT[64 * 36];
  __shared__ __align__(16) float hsl[32 * 65];
  __shared__ __align__(16) float bcs[32];
  const int tile = blockIdx.x;
  const int b    = blockIdx.y;
  const int t0   = tile * 32;
  const int nt   = min(32, NSn - t0);
  const int tid  = threadIdx.x;

  for (int e = tid; e < 32 * 64; e += 256) {
    int i = e >> 6, k = e & 63;
    WcT[k * 36 + i] = W_cs[e];
  }
  for (int e = tid; e < nt * 64; e += 256) {
    int t = e >> 6, k = e & 63;
    hsl[t * 65 + k] = hs[((size_t)b * NSn + t0 + t) * GHn + k];
  }
  if (tid < 32) bcs[tid] = b_cs[tid];
  __syncthreads();

  const int oq = tid & 7;
  const int t  = tid >> 3;
  if (t < nt) {
    float4 acc = *(const float4*)&bcs[oq * 4];
    const float* hr = &hsl[t * 65];
#pragma unroll 4
    for (int k = 0; k < 64; ++k) {
      float hv = hr[k];
      float4 w = *(const float4*)&WcT[k * 36 + oq * 4];
      acc.x = fmaf(w.x, hv, acc.x);
      acc.y = fmaf(w.y, hv, acc.y);
      acc.z = fmaf(w.z, hv, acc.z);
      acc.w = fmaf(w.w, hv, acc.w);
    }
    *(float4*)&cs[((size_t)b * NSn + t0 + t) * 32 + oq * 4] = acc;
  }
}

__global__ __launch_bounds__(256) void out_kernel(const float* __restrict__ x,
                                                  const float* __restrict__ cs,
                                                  const float* __restrict__ W1,
                                                  const float* __restrict__ b1,
                                                  const float* __restrict__ W2,
                                                  const float* __restrict__ b2,
                                                  float* __restrict__ out) {
  __shared__ __align__(16) float A[33 * 65];
  __shared__ __align__(16) float W1T[64 * 68];
  __shared__ __align__(16) float W2T[64 * 36];
  __shared__ __align__(16) float h1loc[33 * 65];
  __shared__ __align__(16) float yloc[33 * 32];
  __shared__ __align__(16) float bb1[64];
  __shared__ __align__(16) float bb2[32];

  const int fb  = blockIdx.x;
  const int b   = blockIdx.y;
  const int f0  = fb * 32;
  const int nf  = min(33, NFn - f0);
  const int tid = threadIdx.x;

  for (int e = tid; e < 64 * 64; e += 256) {
    int o = e >> 6, k = e & 63;
    W1T[k * 68 + o] = W1[e];
  }
  for (int e = tid; e < 32 * 64; e += 256) {
    int o = e >> 6, k = e & 63;
    W2T[k * 36 + o] = W2[e];
  }
  if (tid < 64) bb1[tid] = b1[tid];
  if (tid < 32) bb2[tid] = b2[tid];

  for (int e = tid; e < 33 * 32; e += 256) {
    int lf = e >> 5, k = e & 31;
    int g = (f0 + lf) * 16 + k;
    A[lf * 65 + k] = (lf < nf && g < Tn) ? x[(size_t)b * Tn + g] : 0.0f;
  }
  for (int e = tid; e < 33 * 32; e += 256) {
    int lf = e >> 5, k = e & 31;
    int ts = max((f0 + lf) / 3 - 1, 0);
    A[lf * 65 + 32 + k] = (lf < nf) ? cs[((size_t)b * NSn + ts) * 32 + k] : 0.0f;
  }
  __syncthreads();

  for (int it = tid; it < 33 * 16; it += 256) {
    int lf = it >> 4, oq = it & 15;
    float4 acc = *(const float4*)&bb1[oq * 4];
    const float* ar = &A[lf * 65];
#pragma unroll 4
    for (int k = 0; k < 64; ++k) {
      float av = ar[k];
      float4 w = *(const float4*)&W1T[k * 68 + oq * 4];
      acc.x = fmaf(w.x, av, acc.x);
      acc.y = fmaf(w.y, av, acc.y);
      acc.z = fmaf(w.z, av, acc.z);
      acc.w = fmaf(w.w, av, acc.w);
    }
    acc.x = fmaxf(acc.x, 0.0f); acc.y = fmaxf(acc.y, 0.0f);
    acc.z = fmaxf(acc.z, 0.0f); acc.w = fmaxf(acc.w, 0.0f);
    *(float4*)&h1loc[lf * 65 + oq * 4] = acc;
  }
  __syncthreads();

  for (int it = tid; it < 33 * 8; it += 256) {
    int lf = it >> 3, oq = it & 7;
    float4 acc = *(const float4*)&bb2[oq * 4];
    const float* hr = &h1loc[lf * 65];
#pragma unroll 4
    for (int k = 0; k < 64; ++k) {
      float hv = hr[k];
      float4 w = *(const float4*)&W2T[k * 36 + oq * 4];
      acc.x = fmaf(w.x, hv, acc.x);
      acc.y = fmaf(w.y, hv, acc.y);
      acc.z = fmaf(w.z, hv, acc.z);
      acc.w = fmaf(w.w, hv, acc.w);
    }
    *(float4*)&yloc[lf * 32 + oq * 4] = acc;
  }
  __syncthreads();

  const int s0 = f0 * 16 + 16;
  const int s1 = min(s0 + 512, Tn);
  for (int s = s0 + tid; s < s1; s += 256) {
    int f1  = s >> 4;
    int o1  = s & 15;
    int lf1 = f1 - f0;
    float v = yloc[(lf1 - 1) * 32 + o1 + 16];
    if (lf1 < nf) v += yloc[lf1 * 32 + o1];
    out[(size_t)b * Tn + s] = v;
  }
  if (fb == 0 && tid < 16) out[(size_t)b * Tn + tid] = yloc[tid];
}

// ---------------------------------------------------------------------------
extern "C" void kernel_launch(void* const* d_in, const int* in_sizes, int n_in,
                              void* d_out, int out_size, void* d_ws, size_t ws_size,
                              hipStream_t stream) {
  const float* x    = (const float*)d_in[0];
  const float* W_ih = (const float*)d_in[1];
  const float* W_hh = (const float*)d_in[2];
  const float* b_ih = (const float*)d_in[3];
  const float* b_hh = (const float*)d_in[4];
  const float* W_cs = (const float*)d_in[5];
  const float* b_cs = (const float*)d_in[6];
  const float* W1   = (const float*)d_in[7];
  const float* b1   = (const float*)d_in[8];
  const float* W2   = (const float*)d_in[9];
  const float* b2   = (const float*)d_in[10];
  float* out = (float*)d_out;

  const size_t hsN = (size_t)Bn * NSn * GHn;   // 32.7 MB
  const size_t uN  = (size_t)Bn * NFn * GHn;   // 98.3 MB
  const size_t dN  = hsN;                      // 32.7 MB
  const size_t giN = (size_t)Bn * NSn * G3n;   // 98.2 MB (fallback only)

  if (ws_size >= (hsN + uN + dN) * sizeof(float)) {
    // Fast path: fused gi-producer/gru/U kernel (GI stays in LDS).
    float* hs = (float*)d_ws;
    float* U  = hs + hsN;
    float* d  = U + uN;
    fused_kernel<<<Bn + Bn * 8, 192, 0, stream>>>(x, W_ih, b_ih, W_hh, b_hh,
                                                  W1, b1, hs, U);
    d_kernel<<<dim3(32, Bn), 256, 0, stream>>>(hs, W_cs, b_cs, W1, d);
    out2_kernel<<<dim3(94, Bn), 256, 0, stream>>>(U, d, W2, b2, out);
  } else {
    // Small-ws fallback: round-0 proven pipeline (needs giN + hsN).
    float* GI = (float*)d_ws;
    float* hs = GI + giN;
    float* cs = GI;
    gi_kernel<<<dim3(32, Bn), 192, 0, stream>>>(x, W_ih, b_ih, GI);
    gru_kernel<<<Bn, 64, 0, stream>>>(GI, W_hh, b_hh, hs);
    cs_kernel<<<dim3(32, Bn), 256, 0, stream>>>(hs, W_cs, b_cs, cs);
    out_kernel<<<dim3(94, Bn), 256, 0, stream>>>(x, cs, W1, b1, W2, b2, out);
  }
}